// Round 10
// baseline (270.861 us; speedup 1.0000x reference)
//
#include <hip/hip_runtime.h>
#include <hip/hip_bf16.h>
#include <math.h>

// Problem constants (fixed by reference)
#define NNODES 8191      // tree nodes, ids 0..8190 (topological: children < parent)
#define ROOT   8190
#define NROWS  8192      // tree nodes + appended focal row
#define FOCALR 8191
#define NLEAF  4096
#define HID    512
#define EDIM   2050

// Output layout (fp32 elements, concat in return order)
#define OUT_LOGITS 0
#define OUT_PROBS  8191
#define OUT_EF     16382
#define OUT_EMB    16807932   // 16382 + 8191*2050
#define OUT_FOCAL  21002236   // + 8192*512

typedef float  f32x4 __attribute__((ext_vector_type(4)));
typedef float  f32x2 __attribute__((ext_vector_type(2)));
typedef float  floatx4 __attribute__((ext_vector_type(4)));
typedef short  short8 __attribute__((ext_vector_type(8)));
typedef unsigned short u16;
typedef unsigned short u16x8 __attribute__((ext_vector_type(8)));
typedef unsigned short u16x4 __attribute__((ext_vector_type(4)));

__device__ __forceinline__ f32x4 ldg4(const float* p) { return *(const f32x4*)p; }
__device__ __forceinline__ f32x2 ldg2(const float* p) { return *(const f32x2*)p; }
__device__ __forceinline__ void stg4(float* p, f32x4 v) { *(f32x4*)p = v; }

// ---- L2-bypass (coherence-point) ops for same-kernel cross-wave handoff ----
// Proven protocol (267us run). Row layout: lane owns j0 = lane*4 floats; chunk2 at
// +1024 bytes => each instruction is wave-contiguous 1KB.
__device__ __forceinline__ void st_row(float* p, f32x4 v0, f32x4 v1) {
    asm volatile("global_store_dwordx4 %0, %1, off sc0 sc1\n\t"
                 "global_store_dwordx4 %0, %2, off offset:1024 sc0 sc1"
                 :: "v"(p), "v"(v0), "v"(v1) : "memory");
}
__device__ __forceinline__ void st_wt1(float* p, float v) {
    asm volatile("global_store_dword %0, %1, off sc0 sc1" :: "v"(p), "v"(v) : "memory");
}
__device__ __forceinline__ void st_flag_ordered(float* p, float v) {
    asm volatile("s_waitcnt vmcnt(0)\n\tglobal_store_dword %0, %1, off sc0 sc1"
                 :: "v"(p), "v"(v) : "memory");
}
__device__ __forceinline__ void ld1_sc(const float* p, float& v) {
    asm volatile("global_load_dword %0, %1, off sc0 sc1\n\ts_waitcnt vmcnt(0)"
                 : "=&v"(v) : "v"(p) : "memory");
}
__device__ __forceinline__ void spin1(const float* pc, float& cv) {
    for (;;) {
        asm volatile("global_load_dword %0, %1, off sc0 sc1\n\ts_waitcnt vmcnt(0)"
                     : "=&v"(cv) : "v"(pc) : "memory");
        if (cv > 0.0f) break;
        __builtin_amdgcn_s_sleep(1);
    }
}
__device__ __forceinline__ void spin2(const float* pa, const float* pb,
                                      float& va, float& vb) {
    for (;;) {
        asm volatile("global_load_dword %0, %2, off sc0 sc1\n\t"
                     "global_load_dword %1, %3, off sc0 sc1\n\t"
                     "s_waitcnt vmcnt(0)"
                     : "=&v"(va), "=&v"(vb) : "v"(pa), "v"(pb) : "memory");
        if (va > 0.0f && vb > 0.0f) break;
        __builtin_amdgcn_s_sleep(1);
    }
}
__device__ __forceinline__ void spin3(const float* pa, const float* pb,
                                      const float* pc, float& va, float& vb, float& vc) {
    for (;;) {
        asm volatile("global_load_dword %0, %3, off sc0 sc1\n\t"
                     "global_load_dword %1, %4, off sc0 sc1\n\t"
                     "global_load_dword %2, %5, off sc0 sc1\n\t"
                     "s_waitcnt vmcnt(0)"
                     : "=&v"(va), "=&v"(vb), "=&v"(vc)
                     : "v"(pa), "v"(pb), "v"(pc) : "memory");
        if (va > 0.0f && vb > 0.0f && vc > 0.0f) break;
        __builtin_amdgcn_s_sleep(1);
    }
}
__device__ __forceinline__ void spin4(const float* p0, const float* p1,
                                      const float* p2, const float* p3,
                                      float& v0, float& v1, float& v2, float& v3) {
    for (;;) {
        asm volatile("global_load_dword %0, %4, off sc0 sc1\n\t"
                     "global_load_dword %1, %5, off sc0 sc1\n\t"
                     "global_load_dword %2, %6, off sc0 sc1\n\t"
                     "global_load_dword %3, %7, off sc0 sc1\n\t"
                     "s_waitcnt vmcnt(0)"
                     : "=&v"(v0), "=&v"(v1), "=&v"(v2), "=&v"(v3)
                     : "v"(p0), "v"(p1), "v"(p2), "v"(p3) : "memory");
        if (v0 > 0.0f && v1 > 0.0f && v2 > 0.0f && v3 > 0.0f) break;
        __builtin_amdgcn_s_sleep(1);
    }
}
__device__ __forceinline__ void rows1_cv(const float* p, f32x4& a0, f32x4& a1) {
    asm volatile("global_load_dwordx4 %0, %2, off sc0 sc1\n\t"
                 "global_load_dwordx4 %1, %2, off offset:1024 sc0 sc1\n\t"
                 "s_waitcnt vmcnt(0)"
                 : "=&v"(a0), "=&v"(a1) : "v"(p) : "memory");
}
__device__ __forceinline__ void rows2_cv(const float* p0, const float* p1,
                                         f32x4& a0, f32x4& a1, f32x4& b0, f32x4& b1) {
    asm volatile("global_load_dwordx4 %0, %4, off sc0 sc1\n\t"
                 "global_load_dwordx4 %1, %4, off offset:1024 sc0 sc1\n\t"
                 "global_load_dwordx4 %2, %5, off sc0 sc1\n\t"
                 "global_load_dwordx4 %3, %5, off offset:1024 sc0 sc1\n\t"
                 "s_waitcnt vmcnt(0)"
                 : "=&v"(a0), "=&v"(a1), "=&v"(b0), "=&v"(b1)
                 : "v"(p0), "v"(p1) : "memory");
}
__device__ __forceinline__ void rows3_cv(const float* p0, const float* p1,
                                         const float* p2,
                                         f32x4& a0, f32x4& a1, f32x4& b0, f32x4& b1,
                                         f32x4& c0, f32x4& c1) {
    asm volatile("global_load_dwordx4 %0, %6, off sc0 sc1\n\t"
                 "global_load_dwordx4 %1, %6, off offset:1024 sc0 sc1\n\t"
                 "global_load_dwordx4 %2, %7, off sc0 sc1\n\t"
                 "global_load_dwordx4 %3, %7, off offset:1024 sc0 sc1\n\t"
                 "global_load_dwordx4 %4, %8, off sc0 sc1\n\t"
                 "global_load_dwordx4 %5, %8, off offset:1024 sc0 sc1\n\t"
                 "s_waitcnt vmcnt(0)"
                 : "=&v"(a0), "=&v"(a1), "=&v"(b0), "=&v"(b1), "=&v"(c0), "=&v"(c1)
                 : "v"(p0), "v"(p1), "v"(p2) : "memory");
}
__device__ __forceinline__ void rows4_cv(const float* p0, const float* p1,
                                         const float* p2, const float* p3,
                                         f32x4& a0, f32x4& a1, f32x4& b0, f32x4& b1,
                                         f32x4& c0, f32x4& c1, f32x4& d0, f32x4& d1) {
    asm volatile("global_load_dwordx4 %0, %8, off sc0 sc1\n\t"
                 "global_load_dwordx4 %1, %8, off offset:1024 sc0 sc1\n\t"
                 "global_load_dwordx4 %2, %9, off sc0 sc1\n\t"
                 "global_load_dwordx4 %3, %9, off offset:1024 sc0 sc1\n\t"
                 "global_load_dwordx4 %4, %10, off sc0 sc1\n\t"
                 "global_load_dwordx4 %5, %10, off offset:1024 sc0 sc1\n\t"
                 "global_load_dwordx4 %6, %11, off sc0 sc1\n\t"
                 "global_load_dwordx4 %7, %11, off offset:1024 sc0 sc1\n\t"
                 "s_waitcnt vmcnt(0)"
                 : "=&v"(a0), "=&v"(a1), "=&v"(b0), "=&v"(b1),
                   "=&v"(c0), "=&v"(c1), "=&v"(d0), "=&v"(d1)
                 : "v"(p0), "v"(p1), "v"(p2), "v"(p3) : "memory");
}
__device__ __forceinline__ f32x4 fma4(f32x4 s, float cv, f32x4 pv) { return s + cv * pv; }

__device__ __forceinline__ u16 f2bf(float x) {
    union { float f; unsigned u; } u; u.f = x;
    unsigned r = u.u + 0x7fffu + ((u.u >> 16) & 1u);   // RNE, finite inputs
    return (u16)(r >> 16);
}
__device__ __forceinline__ float b2f(u16 h) {
    union { unsigned u; float f; } x; x.u = ((unsigned)h) << 16; return x.f;
}

// ---------------- stage1: postpre (bids 0-255) + transposes (256-1023) + seed (1024) --
// Proven version (2-level dependency skip). Postpre is latency-bound: transpose/seed
// blocks run in its shadow and terminate unconditionally.
// NOTE (r8 lesson): do NOT co-schedule extra LLC traffic with the chain.
__global__ __launch_bounds__(256) void stage1_kernel(const int* __restrict__ ns,
                                                     const int* __restrict__ ch0,
                                                     const int* __restrict__ ch1,
                                                     const int* __restrict__ par,
                                                     const float* __restrict__ W1,
                                                     float* __restrict__ c,
                                                     float* __restrict__ ypost,
                                                     float* __restrict__ y,
                                                     float* __restrict__ flag2,
                                                     const float* __restrict__ W2,
                                                     const float* __restrict__ Wh2,
                                                     const float* __restrict__ Wh1,
                                                     u16* __restrict__ wte,
                                                     u16* __restrict__ wt2,
                                                     u16* __restrict__ WTz1,
                                                     const int* __restrict__ cfl,
                                                     float* __restrict__ outf,
                                                     const float* __restrict__ bh1,
                                                     float* __restrict__ bprime,
                                                     const float* __restrict__ bh3,
                                                     float* __restrict__ outlog,
                                                     float* __restrict__ hfflag) {
    __shared__ float tile[32][33];
    int bid = blockIdx.x, tid = threadIdx.x;

    if (bid < 256) {
        // ======== fused belief prop with 2-LEVEL DEPENDENCY SKIP (proven, verbatim) ==
        int gtid = bid * 256 + tid;
        int wave = gtid >> 6, lane = gtid & 63;
        int j0 = lane * 4;

        // ---- postorder ----
        for (int u = NLEAF + wave; u < NNODES; u += 1024) {
            int a = ch0[u], b = ch1[u];
            int la = ns[a], lb = ns[b];
            const float *ra0, *ra1, *rb0, *rb1;
            int ga0 = -1, ga1 = -1, gb0 = -1, gb1 = -1;
            if (la >= 0) { ra0 = W1 + (long)la * HID; ra1 = ra0; }
            else {
                int x0 = ch0[a], x1 = ch1[a];
                int n0 = ns[x0], n1 = ns[x1];
                if (n0 >= 0) ra0 = W1 + (long)n0 * HID;
                else { ra0 = ypost + (long)x0 * HID; ga0 = x0; }
                if (n1 >= 0) ra1 = W1 + (long)n1 * HID;
                else { ra1 = ypost + (long)x1 * HID; ga1 = x1; }
            }
            if (lb >= 0) { rb0 = W1 + (long)lb * HID; rb1 = rb0; }
            else {
                int x0 = ch0[b], x1 = ch1[b];
                int n0 = ns[x0], n1 = ns[x1];
                if (n0 >= 0) rb0 = W1 + (long)n0 * HID;
                else { rb0 = ypost + (long)x0 * HID; gb0 = x0; }
                if (n1 >= 0) rb1 = W1 + (long)n1 * HID;
                else { rb1 = ypost + (long)x1 * HID; gb1 = x1; }
            }
            float ca0 = 0.f, ca1 = 0.f, cb0 = 0.f, cb1 = 0.f;
            if ((ga0 | ga1 | gb0 | gb1) >= 0) {
                int w0 = ga0 >= 0 ? ga0 : ga1 >= 0 ? ga1 : gb0 >= 0 ? gb0 : gb1;
                float s0, s1, s2, s3;
                spin4(c + (ga0 >= 0 ? ga0 : w0), c + (ga1 >= 0 ? ga1 : w0),
                      c + (gb0 >= 0 ? gb0 : w0), c + (gb1 >= 0 ? gb1 : w0),
                      s0, s1, s2, s3);
                if (ga0 >= 0) ca0 = s0;
                if (ga1 >= 0) ca1 = s1;
                if (gb0 >= 0) cb0 = s2;
                if (gb1 >= 0) cb1 = s3;
            }
            f32x4 qa00, qa01, qa10, qa11, qb00, qb01, qb10, qb11;
            rows4_cv(ra0 + j0, ra1 + j0, rb0 + j0, rb1 + j0,
                     qa00, qa01, qa10, qa11, qb00, qb01, qb10, qb11);
            f32x4 A0, A1, B0, B1; float cA, cB;
            if (la >= 0) { cA = 0.0f; A0 = qa00; A1 = qa01; }
            else {
                cA = 1.0f / (3.0f - (ca0 + ca1));
                A0 = (qa00 + qa10) * cA; A1 = (qa01 + qa11) * cA;
            }
            if (lb >= 0) { cB = 0.0f; B0 = qb00; B1 = qb01; }
            else {
                cB = 1.0f / (3.0f - (cb0 + cb1));
                B0 = (qb00 + qb10) * cB; B1 = (qb01 + qb11) * cB;
            }
            float cu = 1.0f / (3.0f - (cA + cB));
            st_row(ypost + (long)u * HID + j0, (A0 + B0) * cu, (A1 + B1) * cu);
            if (lane == 0) st_flag_ordered(&c[u], cu);
        }

        // ---- preorder ----
        for (int u = ROOT - wave; u >= NLEAF; u -= 1024) {
            float* dst = y + (long)u * HID + j0;
            if (u == ROOT) {
                float cr;
                spin1(c + ROOT, cr);
                f32x4 s0, s1;
                rows1_cv(ypost + (long)ROOT * HID + j0, s0, s1);
                st_row(dst, s0, s1);
            } else {
                int p = par[u];
                if (p == ROOT) {
                    float cr, cu;
                    spin2(c + ROOT, c + u, cr, cu);
                    f32x4 s0, s1, r0, r1;
                    rows2_cv(ypost + (long)u * HID + j0, ypost + (long)ROOT * HID + j0,
                             s0, s1, r0, r1);
                    st_row(dst, fma4(s0, cu, r0), fma4(s1, cu, r1));
                } else {
                    int gp = par[p];
                    float f2, cu, cp;
                    spin3(flag2 + gp, c + u, c + p, f2, cu, cp);
                    f32x4 s0, s1, pp0, pp1, gg0, gg1;
                    rows3_cv(ypost + (long)u * HID + j0, ypost + (long)p * HID + j0,
                             y + (long)gp * HID + j0, s0, s1, pp0, pp1, gg0, gg1);
                    f32x4 yp0 = fma4(pp0, cp, gg0);
                    f32x4 yp1 = fma4(pp1, cp, gg1);
                    st_row(dst, fma4(s0, cu, yp0), fma4(s1, cu, yp1));
                }
            }
            if (lane == 0) st_flag_ordered(&flag2[u], 1.0f);
        }
        return;
    }

    if (bid < 1024) {
        // ======== static transposes: 3 sections of (512x512 fp32) -> bf16 [n][k] =====
        int t = bid - 256;
        int bx = t & 15, by = t >> 4;
        int sec = by >> 4, kt = by & 15;
        int tx = tid & 31, ty = tid >> 5;
        int n0 = bx * 32, k0 = kt * 32;
        const float* src = (sec == 0) ? W2 : (sec == 1) ? Wh2 : (Wh1 + (long)1024 * HID);
        u16* dst = (sec == 0) ? wte : (sec == 1) ? wt2 : WTz1;
        int ld = (sec == 2) ? 1024 : 512;
        int koff = (sec == 2) ? 512 : 0;
#pragma unroll
        for (int i = 0; i < 4; i++)
            tile[ty + i * 8][tx] = src[(long)(k0 + ty + i * 8) * HID + n0 + tx];
        __syncthreads();
#pragma unroll
        for (int i = 0; i < 4; i++)
            dst[(long)(n0 + ty + i * 8) * ld + koff + k0 + tx] = f2bf(tile[tx][ty + i * 8]);
        return;
    }

    // ======== seed block: focal one-hot, logits = b3, bprime = bh1, hfflag = 0 =======
    int cf = cfl[0];
    for (int i = tid; i < NLEAF; i += 256) outf[i] = (i == cf) ? 1.0f : 0.0f;
    float b3v = bh3[0];
    for (int i = tid; i < NNODES; i += 256) outlog[i] = b3v;
    for (int i = tid; i < 512; i += 256) bprime[i] = bh1[i];
    if (tid < 4) hfflag[tid] = 0.0f;
}

// ---------------- GCN neighbor aggregation in 512-d (layer 1) -------------------------
// REDIR: leaf/focal rows read directly from W1 (y rows only exist for internal nodes)
__global__ __launch_bounds__(128) void gcn_agg_kernel(const float* __restrict__ xinf,
                                                      const int* __restrict__ neigh,
                                                      const float* __restrict__ bias,
                                                      const int* __restrict__ ns,
                                                      const int* __restrict__ cfl,
                                                      const float* __restrict__ W1,
                                                      u16* __restrict__ xoutb) {
    int u = blockIdx.x;
    int t = threadIdx.x;
    int n0 = neigh[u * 3 + 0], n1 = neigh[u * 3 + 1], n2 = neigh[u * 3 + 2];
    float deg = 1.0f + (n0 >= 0) + (n1 >= 0) + (n2 >= 0);
    auto rowp = [&](int v) -> const float* {
        if (v == FOCALR) return W1 + (long)cfl[0] * HID;
        int nv = ns[v];
        return (nv >= 0) ? (W1 + (long)nv * HID) : (xinf + (long)v * HID);
    };
    f32x4 s = ldg4(rowp(u) + t * 4);
    if (n0 >= 0) s += ldg4(rowp(n0) + t * 4);
    if (n1 >= 0) s += ldg4(rowp(n1) + t * 4);
    if (n2 >= 0) s += ldg4(rowp(n2) + t * 4);
    s *= (1.0f / deg);
    s += ldg4(bias + t * 4);
    s.x = fmaxf(s.x, 0.f); s.y = fmaxf(s.y, 0.f); s.z = fmaxf(s.z, 0.f); s.w = fmaxf(s.w, 0.f);
    u16x4 h; h[0] = f2bf(s.x); h[1] = f2bf(s.y); h[2] = f2bf(s.z); h[3] = f2bf(s.w);
    *(u16x4*)(xoutb + (long)u * HID + t * 4) = h;
}

// ---------------- bf16 MFMA GEMM v5: 64x128 tile, dbuf pipeline, 1D grid --------------
// bid<512: GEMM tile (bn = (bid&3)*128, bm = (bid>>2)*64).
// LOG=1: logits[row] += v * W3[col] via wave-reduce + atomics (outlog seeded with b3).
// AGG=1: A rows generated on the fly = mean of {self, <=3 neighbors} h_bf rows.
// EF=1:  bids >= 512 are ef-row writer blocks (2 rows each), overlapped with the GEMM.
// PUBFAN=1: the 4 blocks owning row FOCALR sc-publish the hf row + flags; bids >= 512
//        are zprep/bvec consumer blocks gated on those flags (proven stage1 protocol).
//        Consumer LDS overlays the GEMM's As buffer so static LDS stays 48KB (3/CU).
__device__ __forceinline__ int sw_idx(int row, int kc8) {
    return (row * 8 + (kc8 ^ (row & 7))) * 8;   // u16 index of 16B slot
}

template <int ACT, int AGEN, int LOG, int AGG, int EF, int PUBFAN>
__global__ __launch_bounds__(256, 3) void gemm_v5(const u16* __restrict__ Abf,
                                                  const u16* __restrict__ WT,
                                                  const float* __restrict__ bias,
                                                  const int* __restrict__ bc,
                                                  const float* __restrict__ tv,
                                                  const float* __restrict__ isr,
                                                  const float* __restrict__ Wtail,
                                                  float* __restrict__ Cf,
                                                  u16* __restrict__ Cbf,
                                                  int M, int K,
                                                  const float* __restrict__ W3,
                                                  float* __restrict__ outlog,
                                                  const int* __restrict__ neigh,
                                                  const float* __restrict__ embf,
                                                  float* __restrict__ efout,
                                                  const float* __restrict__ Wh1,
                                                  u16* __restrict__ WTz1,
                                                  float* __restrict__ bprime,
                                                  float* __restrict__ hfsc,
                                                  float* __restrict__ hfflag) {
    __shared__ u16 As[2][64 * 64];
    __shared__ u16 Ws[2][128 * 64];
    if (EF && blockIdx.x >= 512) {
        // ---- ef rows: [hf | ht | |hf-ht| | hf*ht | t_norm | is_root], 2 rows/block ---
        int eb = blockIdx.x - 512;
        int u = eb * 2 + (threadIdx.x >> 7);
        int t = threadIdx.x & 127;
        if (u < NNODES) {
            const float* hfp = embf + (long)FOCALR * HID;
            const float* ht = embf + (long)bc[u] * HID;
            f32x4 f = ldg4(hfp + 4 * t);
            f32x4 h = ldg4(ht + 4 * t);
            float* row = efout + (long)u * EDIM;
            *(f32x4*)(row + 4 * t) = f;
            *(f32x4*)(row + 512 + 4 * t) = h;
            f32x4 d;
            d.x = fabsf(f.x - h.x); d.y = fabsf(f.y - h.y);
            d.z = fabsf(f.z - h.z); d.w = fabsf(f.w - h.w);
            *(f32x4*)(row + 1024 + 4 * t) = d;
            *(f32x4*)(row + 1536 + 4 * t) = f * h;
            if (t == 0) {
                row[2048] = tv[u];
                row[2049] = isr[u];
            }
        }
        return;
    }
    if (PUBFAN && blockIdx.x >= 512) {
        // ---- fan consumers: gate on hf publication, then zprep / bvec ---------------
        int fb = blockIdx.x - 512;
        int tid = threadIdx.x;
        float g0, g1, g2, g3;
        spin4(hfflag, hfflag + 1, hfflag + 2, hfflag + 3, g0, g1, g2, g3);
        float* tBf = (float*)&As[0][0];          // overlay into GEMM LDS (16KB avail)
        float* tDf = tBf + 32 * 33;
        if (fb < 256) {
            // zprep: WTz1[n][k] (k<512) = bf16(W_B + hf[k]*W_D)
            int tx = tid & 31, ty = tid >> 5;
            int n0 = (fb & 15) * 32, k0 = (fb >> 4) * 32;
            float hfk;
            ld1_sc(hfsc + k0 + tx, hfk);
#pragma unroll
            for (int i = 0; i < 4; i++) {
                tBf[(ty + i * 8) * 33 + tx] = Wh1[(long)(512 + k0 + ty + i * 8) * HID + n0 + tx];
                tDf[(ty + i * 8) * 33 + tx] = Wh1[(long)(1536 + k0 + ty + i * 8) * HID + n0 + tx];
            }
            __syncthreads();
#pragma unroll
            for (int i = 0; i < 4; i++) {
                WTz1[(long)(n0 + ty + i * 8) * 1024 + k0 + tx] =
                    f2bf(tBf[tx * 33 + ty + i * 8] + hfk * tDf[tx * 33 + ty + i * 8]);
            }
        } else {
            // bvec partial: atomicAdd into bprime (seeded = bh1 in stage1)
            int kc = fb - 256;
            if (tid < 64) {
                float v;
                ld1_sc(hfsc + kc * 64 + tid, v);
                tBf[tid] = v;
            }
            __syncthreads();
            float s0 = 0.0f, s1 = 0.0f;
#pragma unroll 4
            for (int k2 = 0; k2 < 64; k2++) {
                float h = tBf[k2];
                int k = kc * 64 + k2;
                s0 += h * Wh1[(long)k * HID + tid];
                s1 += h * Wh1[(long)k * HID + 256 + tid];
            }
            atomicAdd(bprime + tid, s0);
            atomicAdd(bprime + 256 + tid, s1);
        }
        return;
    }
    const int tid = threadIdx.x, lane = tid & 63;
    const int wm = (tid >> 6) >> 1, wn = (tid >> 6) & 1;
    const int bid1 = blockIdx.x;
    const int bn = (bid1 & 3) * 128, bm = (bid1 >> 2) * 64;
    const int kq = lane >> 4, lr = lane & 15;
    const int srow = tid >> 3, schunk = tid & 7;
    const int nk = K >> 6;
    floatx4 acc[2][4] = {};

    int btc[2];
    if (AGEN) {
#pragma unroll
        for (int i = 0; i < 2; i++) {
            int gr = bm + srow + i * 32;
            btc[i] = bc[gr < M ? gr : 0];
        }
    }
    int nbr[2][3];
    float invdeg[2];
    if (AGG) {
#pragma unroll
        for (int i = 0; i < 2; i++) {
            int gr = bm + srow + i * 32;
            int v0 = neigh[gr * 3 + 0], v1 = neigh[gr * 3 + 1], v2 = neigh[gr * 3 + 2];
            nbr[i][0] = v0; nbr[i][1] = v1; nbr[i][2] = v2;
            invdeg[i] = 1.0f / (1.0f + (v0 >= 0) + (v1 >= 0) + (v2 >= 0));
        }
    }

    u16x8 pf_hf, pf_a[2], pf_b[4], pf_n[2][3];

    auto prefetch = [&](int kk) {
        if (AGEN) {
            int cb = (kk & 7) * 64 + schunk * 8;
            pf_hf = *(const u16x8*)(Abf + (long)FOCALR * HID + cb);
#pragma unroll
            for (int i = 0; i < 2; i++)
                pf_a[i] = *(const u16x8*)(Abf + (long)btc[i] * HID + cb);
        } else if (AGG) {
            long kof = (long)(kk * 64 + schunk * 8);
#pragma unroll
            for (int i = 0; i < 2; i++) {
                int gr = bm + srow + i * 32;
                pf_a[i] = *(const u16x8*)(Abf + (long)gr * HID + kof);
#pragma unroll
                for (int k = 0; k < 3; k++)
                    pf_n[i][k] = (nbr[i][k] >= 0)
                        ? *(const u16x8*)(Abf + (long)nbr[i][k] * HID + kof)
                        : (u16x8){0, 0, 0, 0, 0, 0, 0, 0};
            }
        } else {
            long kof = (long)(kk * 64 + schunk * 8);
#pragma unroll
            for (int i = 0; i < 2; i++) {
                int gr = bm + srow + i * 32;
                if (gr < M) pf_a[i] = *(const u16x8*)(Abf + (long)gr * K + kof);
                else        pf_a[i] = (u16x8){0,0,0,0,0,0,0,0};
            }
        }
#pragma unroll
        for (int i = 0; i < 4; i++)
            pf_b[i] = *(const u16x8*)(WT + (long)(bn + srow + i * 32) * K + kk * 64 + schunk * 8);
    };

    auto commit = [&](int kk, int buf) {
        if (AGEN) {
            int sec = kk >> 3;
#pragma unroll
            for (int i = 0; i < 2; i++) {
                u16x8 v;
                if (sec == 0) v = pf_a[i];
                else {
#pragma unroll
                    for (int q = 0; q < 8; q++) v[q] = f2bf(fabsf(b2f(pf_hf[q]) - b2f(pf_a[i][q])));
                }
                if (bm + srow + i * 32 >= M) v = (u16x8){0,0,0,0,0,0,0,0};
                *(u16x8*)&As[buf][sw_idx(srow + i * 32, schunk)] = v;
            }
        } else if (AGG) {
#pragma unroll
            for (int i = 0; i < 2; i++) {
                u16x8 v;
#pragma unroll
                for (int q = 0; q < 8; q++) {
                    float s = b2f(pf_a[i][q]);
                    s += b2f(pf_n[i][0][q]);
                    s += b2f(pf_n[i][1][q]);
                    s += b2f(pf_n[i][2][q]);
                    v[q] = f2bf(s * invdeg[i]);
                }
                *(u16x8*)&As[buf][sw_idx(srow + i * 32, schunk)] = v;
            }
        } else {
#pragma unroll
            for (int i = 0; i < 2; i++)
                *(u16x8*)&As[buf][sw_idx(srow + i * 32, schunk)] = pf_a[i];
        }
#pragma unroll
        for (int i = 0; i < 4; i++)
            *(u16x8*)&Ws[buf][sw_idx(srow + i * 32, schunk)] = pf_b[i];
    };

    prefetch(0);
    commit(0, 0);
    __syncthreads();

    for (int kk = 0; kk < nk; kk++) {
        int cur = kk & 1;
        bool more = (kk + 1) < nk;
        if (more) prefetch(kk + 1);
#pragma unroll
        for (int kc = 0; kc < 2; kc++) {
            short8 af[2], bf8[4];
#pragma unroll
            for (int t2 = 0; t2 < 2; t2++)
                af[t2]  = *(short8*)&As[cur][sw_idx(wm * 32 + t2 * 16 + lr, kc * 4 + kq)];
#pragma unroll
            for (int t2 = 0; t2 < 4; t2++)
                bf8[t2] = *(short8*)&Ws[cur][sw_idx(wn * 64 + t2 * 16 + lr, kc * 4 + kq)];
#pragma unroll
            for (int i2 = 0; i2 < 2; i2++)
#pragma unroll
                for (int j = 0; j < 4; j++)
                    acc[i2][j] = __builtin_amdgcn_mfma_f32_16x16x32_bf16(af[i2], bf8[j], acc[i2][j], 0, 0, 0);
        }
        if (more) {
            __syncthreads();
            commit(kk + 1, cur ^ 1);
            __syncthreads();
        }
    }

    // ---- epilogue: row=(lane>>4)*4+reg, col=lane&15 ----
    float lsum[2][4] = {};
    float w3v[4] = {};
    if (LOG) {
#pragma unroll
        for (int j = 0; j < 4; j++) w3v[j] = W3[bn + wn * 64 + j * 16 + lr];
    }
#pragma unroll
    for (int i = 0; i < 2; i++) {
        int row0 = bm + wm * 32 + i * 16 + kq * 4;
#pragma unroll
        for (int j = 0; j < 4; j++) {
            int col = bn + wn * 64 + j * 16 + lr;
            float bv = bias[col];
            float t0 = 0.f, t1 = 0.f;
            if (AGEN) { t0 = Wtail[col]; t1 = Wtail[512 + col]; }
#pragma unroll
            for (int r = 0; r < 4; r++) {
                int gr = row0 + r;
                if (gr < M) {
                    float v = acc[i][j][r] + bv;
                    if (AGEN) v += tv[gr] * t0 + isr[gr] * t1;
                    if (ACT == 2) v = (v > 0.0f) ? v : (expf(v) - 1.0f);
                    if (LOG) lsum[i][r] += v * w3v[j];
                    if (Cf)  Cf[(long)gr * HID + col] = v;
                    if (Cbf) Cbf[(long)gr * HID + col] = f2bf(v);
                    if (PUBFAN && gr == FOCALR) st_wt1(hfsc + col, v);   // sc publish
                }
            }
        }
    }
    if (LOG) {
#pragma unroll
        for (int i = 0; i < 2; i++) {
            int row0 = bm + wm * 32 + i * 16 + kq * 4;
#pragma unroll
            for (int r = 0; r < 4; r++) {
                float s = lsum[i][r];
                s += __shfl_xor(s, 1);
                s += __shfl_xor(s, 2);
                s += __shfl_xor(s, 4);
                s += __shfl_xor(s, 8);
                if (lr == 0) {
                    int gr = row0 + r;
                    if (gr < M) atomicAdd(outlog + gr, s);
                }
            }
        }
    }
    if (PUBFAN && bm == 8128) {
        // drain every thread's sc stores, then publish this bn-quarter's flag
        asm volatile("s_waitcnt vmcnt(0)" ::: "memory");
        __syncthreads();
        if (tid == 0) st_wt1(hfflag + (bn >> 7), 1.0f);
    }
}

// ---------------- softmax over 8191 logits (single block) -----------------------------
__global__ __launch_bounds__(1024) void softmax_kernel(const float* __restrict__ lg,
                                                       float* __restrict__ probs) {
    __shared__ float red[16];
    __shared__ float gmax_s, gsum_s;
    int t = threadIdx.x, wid = t >> 6, lane = t & 63;
    float m = -3.4e38f;
    for (int i = t; i < NNODES; i += 1024) m = fmaxf(m, lg[i]);
    for (int o = 32; o; o >>= 1) m = fmaxf(m, __shfl_down(m, o));
    if (lane == 0) red[wid] = m;
    __syncthreads();
    if (t == 0) {
        float g = red[0];
        for (int i = 1; i < 16; i++) g = fmaxf(g, red[i]);
        gmax_s = g;
    }
    __syncthreads();
    float gmax = gmax_s;
    float s = 0.0f;
    for (int i = t; i < NNODES; i += 1024) s += expf(lg[i] - gmax);
    for (int o = 32; o; o >>= 1) s += __shfl_down(s, o);
    if (lane == 0) red[wid] = s;
    __syncthreads();
    if (t == 0) {
        float g = 0.0f;
        for (int i = 0; i < 16; i++) g += red[i];
        gsum_s = g;
    }
    __syncthreads();
    float inv = 1.0f / gsum_s;
    for (int i = t; i < NNODES; i += 1024) probs[i] = expf(lg[i] - gmax) * inv;
}

extern "C" void kernel_launch(void* const* d_in, const int* in_sizes, int n_in,
                              void* d_out, int out_size, void* d_ws, size_t ws_size,
                              hipStream_t stream) {
    const int*   ns    = (const int*)d_in[0];
    const int*   ch0   = (const int*)d_in[1];
    const int*   ch1   = (const int*)d_in[2];
    const int*   par   = (const int*)d_in[3];
    const int*   neigh = (const int*)d_in[4];
    const int*   bc    = (const int*)d_in[5];
    const int*   cfl   = (const int*)d_in[6];
    const float* tv    = (const float*)d_in[7];
    const float* isr   = (const float*)d_in[8];
    const float* W1    = (const float*)d_in[9];
    const float* b1    = (const float*)d_in[10];
    const float* W2    = (const float*)d_in[11];
    const float* b2    = (const float*)d_in[12];
    const float* Wh1   = (const float*)d_in[13];
    const float* bh1   = (const float*)d_in[14];
    const float* Wh2   = (const float*)d_in[15];
    const float* bh2   = (const float*)d_in[16];
    const float* Wh3   = (const float*)d_in[17];
    const float* bh3   = (const float*)d_in[18];

    float* out = (float*)d_out;
    float* out_logits = out + OUT_LOGITS;
    float* out_probs  = out + OUT_PROBS;
    float* out_ef     = out + OUT_EF;
    float* out_emb    = out + OUT_EMB;
    float* out_focal  = out + OUT_FOCAL;

    const size_t MB = 1024 * 1024;
    char* ws = (char*)d_ws;
    float* c      = (float*)(ws);                    // 8191 floats
    float* flag2  = (float*)(ws + 40960);            // 8192 floats
    float* buf0   = (float*)(ws + 81920);            // 16 MB: ypost
    float* buf1   = (float*)(ws + 81920 + 16 * MB);  // 16 MB: y -> emb_bf (high half)
    float* buf2   = (float*)(ws + 81920 + 32 * MB);  // 16 MB: h_bf -> z1_bf
    u16*   wte    = (u16*)  (ws + 81920 + 48 * MB);          // 512x512  bf16 = 0.5 MB
    u16*   wt2    = (u16*)  (ws + 81920 + 48 * MB + 512 * 1024);
    u16*   wtz1   = (u16*)  (ws + 81920 + 49 * MB);          // 512x1024 bf16 = 1 MB
    float* bprime = (float*)(ws + 81920 + 50 * MB);          // 512 floats
    float* hfsc   = (float*)(ws + 81920 + 50 * MB + 4096);   // 512 floats (sc hf row)
    float* hfflag = (float*)(ws + 81920 + 50 * MB + 8192);   // 4 floats

    float* ypost  = buf0;
    float* y      = buf1;
    u16*   emb_bf = (u16*)((char*)buf1 + 8 * MB);
    u16*   h_bf   = (u16*)buf2;
    u16*   z1_bf  = (u16*)buf2;

    // stage1: tree recursions + (in their latency shadow) weight transposes, focal
    // one-hot, logits/bprime seeding, hfflag zeroing
    stage1_kernel<<<dim3(1025), dim3(256), 0, stream>>>(ns, ch0, ch1, par, W1, c, ypost,
                                                        y, flag2, W2, Wh2, Wh1, wte, wt2,
                                                        wtz1, cfl, out_focal, bh1, bprime,
                                                        bh3, out_logits, hfflag);
    // GCN layer 1: h_bf = bf16(relu(agg(y) + b1)), leaf/focal rows redirected to W1
    gcn_agg_kernel<<<dim3(NROWS), dim3(128), 0, stream>>>(y, neigh, b1, ns, cfl, W1, h_bf);
    // emb = agg(h_bf) @ W2 + b2 (GCN layer-2 agg fused into A-staging); the 4 blocks
    // owning row FOCALR publish hf; 264 appended blocks run zprep + bvec gated on it
    gemm_v5<0, 0, 0, 1, 0, 1><<<dim3(776), dim3(256), 0, stream>>>(
        h_bf, wte, b2, nullptr, nullptr, nullptr, nullptr, out_emb, emb_bf,
        NROWS, HID, nullptr, nullptr, neigh, nullptr, nullptr,
        Wh1, wtz1, bprime, hfsc, hfflag);
    // z1 = elu([ht | |hf-ht|] @ WTz1 + ...), with ef-row writer blocks overlapped
    gemm_v5<2, 1, 0, 0, 1, 0><<<dim3(4608), dim3(256), 0, stream>>>(
        emb_bf, wtz1, bprime, bc, tv, isr, Wh1 + (long)2048 * HID, nullptr, z1_bf,
        NNODES, 1024, nullptr, nullptr, nullptr, out_emb, out_ef,
        nullptr, nullptr, nullptr, nullptr, nullptr);
    // z2 = elu(z1 @ Wh2 + bh2); logits folded into epilogue (no z2 store at all)
    gemm_v5<2, 0, 1, 0, 0, 0><<<dim3(512), dim3(256), 0, stream>>>(
        z1_bf, wt2, bh2, nullptr, nullptr, nullptr, nullptr, nullptr, nullptr,
        NNODES, HID, Wh3, out_logits, nullptr, nullptr, nullptr,
        nullptr, nullptr, nullptr, nullptr, nullptr);
    softmax_kernel<<<dim3(1), dim3(1024), 0, stream>>>(out_logits, out_probs);
}

// Round 11
// 263.296 us; speedup vs baseline: 1.0287x; 1.0287x over previous
//
#include <hip/hip_runtime.h>
#include <hip/hip_bf16.h>
#include <math.h>

// Problem constants (fixed by reference)
#define NNODES 8191      // tree nodes, ids 0..8190 (topological: children < parent)
#define ROOT   8190
#define NROWS  8192      // tree nodes + appended focal row
#define FOCALR 8191
#define NLEAF  4096
#define HID    512
#define EDIM   2050

// Output layout (fp32 elements, concat in return order)
#define OUT_LOGITS 0
#define OUT_PROBS  8191
#define OUT_EF     16382
#define OUT_EMB    16807932   // 16382 + 8191*2050
#define OUT_FOCAL  21002236   // + 8192*512

typedef float  f32x4 __attribute__((ext_vector_type(4)));
typedef float  f32x2 __attribute__((ext_vector_type(2)));
typedef float  floatx4 __attribute__((ext_vector_type(4)));
typedef short  short8 __attribute__((ext_vector_type(8)));
typedef unsigned short u16;
typedef unsigned short u16x8 __attribute__((ext_vector_type(8)));
typedef unsigned short u16x4 __attribute__((ext_vector_type(4)));

__device__ __forceinline__ f32x4 ldg4(const float* p) { return *(const f32x4*)p; }
__device__ __forceinline__ f32x2 ldg2(const float* p) { return *(const f32x2*)p; }
__device__ __forceinline__ void stg4(float* p, f32x4 v) { *(f32x4*)p = v; }

// ---- L2-bypass (coherence-point) ops for same-kernel cross-wave handoff ----
// Proven protocol (267us run). Row layout: lane owns j0 = lane*4 floats; chunk2 at
// +1024 bytes => each instruction is wave-contiguous 1KB.
__device__ __forceinline__ void st_row(float* p, f32x4 v0, f32x4 v1) {
    asm volatile("global_store_dwordx4 %0, %1, off sc0 sc1\n\t"
                 "global_store_dwordx4 %0, %2, off offset:1024 sc0 sc1"
                 :: "v"(p), "v"(v0), "v"(v1) : "memory");
}
__device__ __forceinline__ void st_flag_ordered(float* p, float v) {
    asm volatile("s_waitcnt vmcnt(0)\n\tglobal_store_dword %0, %1, off sc0 sc1"
                 :: "v"(p), "v"(v) : "memory");
}
__device__ __forceinline__ void spin1(const float* pc, float& cv) {
    for (;;) {
        asm volatile("global_load_dword %0, %1, off sc0 sc1\n\ts_waitcnt vmcnt(0)"
                     : "=&v"(cv) : "v"(pc) : "memory");
        if (cv > 0.0f) break;
        __builtin_amdgcn_s_sleep(1);
    }
}
__device__ __forceinline__ void spin2(const float* pa, const float* pb,
                                      float& va, float& vb) {
    for (;;) {
        asm volatile("global_load_dword %0, %2, off sc0 sc1\n\t"
                     "global_load_dword %1, %3, off sc0 sc1\n\t"
                     "s_waitcnt vmcnt(0)"
                     : "=&v"(va), "=&v"(vb) : "v"(pa), "v"(pb) : "memory");
        if (va > 0.0f && vb > 0.0f) break;
        __builtin_amdgcn_s_sleep(1);
    }
}
__device__ __forceinline__ void spin3(const float* pa, const float* pb,
                                      const float* pc, float& va, float& vb, float& vc) {
    for (;;) {
        asm volatile("global_load_dword %0, %3, off sc0 sc1\n\t"
                     "global_load_dword %1, %4, off sc0 sc1\n\t"
                     "global_load_dword %2, %5, off sc0 sc1\n\t"
                     "s_waitcnt vmcnt(0)"
                     : "=&v"(va), "=&v"(vb), "=&v"(vc)
                     : "v"(pa), "v"(pb), "v"(pc) : "memory");
        if (va > 0.0f && vb > 0.0f && vc > 0.0f) break;
        __builtin_amdgcn_s_sleep(1);
    }
}
__device__ __forceinline__ void spin4(const float* p0, const float* p1,
                                      const float* p2, const float* p3,
                                      float& v0, float& v1, float& v2, float& v3) {
    for (;;) {
        asm volatile("global_load_dword %0, %4, off sc0 sc1\n\t"
                     "global_load_dword %1, %5, off sc0 sc1\n\t"
                     "global_load_dword %2, %6, off sc0 sc1\n\t"
                     "global_load_dword %3, %7, off sc0 sc1\n\t"
                     "s_waitcnt vmcnt(0)"
                     : "=&v"(v0), "=&v"(v1), "=&v"(v2), "=&v"(v3)
                     : "v"(p0), "v"(p1), "v"(p2), "v"(p3) : "memory");
        if (v0 > 0.0f && v1 > 0.0f && v2 > 0.0f && v3 > 0.0f) break;
        __builtin_amdgcn_s_sleep(1);
    }
}
__device__ __forceinline__ void rows1_cv(const float* p, f32x4& a0, f32x4& a1) {
    asm volatile("global_load_dwordx4 %0, %2, off sc0 sc1\n\t"
                 "global_load_dwordx4 %1, %2, off offset:1024 sc0 sc1\n\t"
                 "s_waitcnt vmcnt(0)"
                 : "=&v"(a0), "=&v"(a1) : "v"(p) : "memory");
}
__device__ __forceinline__ void rows2_cv(const float* p0, const float* p1,
                                         f32x4& a0, f32x4& a1, f32x4& b0, f32x4& b1) {
    asm volatile("global_load_dwordx4 %0, %4, off sc0 sc1\n\t"
                 "global_load_dwordx4 %1, %4, off offset:1024 sc0 sc1\n\t"
                 "global_load_dwordx4 %2, %5, off sc0 sc1\n\t"
                 "global_load_dwordx4 %3, %5, off offset:1024 sc0 sc1\n\t"
                 "s_waitcnt vmcnt(0)"
                 : "=&v"(a0), "=&v"(a1), "=&v"(b0), "=&v"(b1)
                 : "v"(p0), "v"(p1) : "memory");
}
__device__ __forceinline__ void rows3_cv(const float* p0, const float* p1,
                                         const float* p2,
                                         f32x4& a0, f32x4& a1, f32x4& b0, f32x4& b1,
                                         f32x4& c0, f32x4& c1) {
    asm volatile("global_load_dwordx4 %0, %6, off sc0 sc1\n\t"
                 "global_load_dwordx4 %1, %6, off offset:1024 sc0 sc1\n\t"
                 "global_load_dwordx4 %2, %7, off sc0 sc1\n\t"
                 "global_load_dwordx4 %3, %7, off offset:1024 sc0 sc1\n\t"
                 "global_load_dwordx4 %4, %8, off sc0 sc1\n\t"
                 "global_load_dwordx4 %5, %8, off offset:1024 sc0 sc1\n\t"
                 "s_waitcnt vmcnt(0)"
                 : "=&v"(a0), "=&v"(a1), "=&v"(b0), "=&v"(b1), "=&v"(c0), "=&v"(c1)
                 : "v"(p0), "v"(p1), "v"(p2) : "memory");
}
__device__ __forceinline__ void rows4_cv(const float* p0, const float* p1,
                                         const float* p2, const float* p3,
                                         f32x4& a0, f32x4& a1, f32x4& b0, f32x4& b1,
                                         f32x4& c0, f32x4& c1, f32x4& d0, f32x4& d1) {
    asm volatile("global_load_dwordx4 %0, %8, off sc0 sc1\n\t"
                 "global_load_dwordx4 %1, %8, off offset:1024 sc0 sc1\n\t"
                 "global_load_dwordx4 %2, %9, off sc0 sc1\n\t"
                 "global_load_dwordx4 %3, %9, off offset:1024 sc0 sc1\n\t"
                 "global_load_dwordx4 %4, %10, off sc0 sc1\n\t"
                 "global_load_dwordx4 %5, %10, off offset:1024 sc0 sc1\n\t"
                 "global_load_dwordx4 %6, %11, off sc0 sc1\n\t"
                 "global_load_dwordx4 %7, %11, off offset:1024 sc0 sc1\n\t"
                 "s_waitcnt vmcnt(0)"
                 : "=&v"(a0), "=&v"(a1), "=&v"(b0), "=&v"(b1),
                   "=&v"(c0), "=&v"(c1), "=&v"(d0), "=&v"(d1)
                 : "v"(p0), "v"(p1), "v"(p2), "v"(p3) : "memory");
}
__device__ __forceinline__ f32x4 fma4(f32x4 s, float cv, f32x4 pv) { return s + cv * pv; }

__device__ __forceinline__ u16 f2bf(float x) {
    union { float f; unsigned u; } u; u.f = x;
    unsigned r = u.u + 0x7fffu + ((u.u >> 16) & 1u);   // RNE, finite inputs
    return (u16)(r >> 16);
}
__device__ __forceinline__ float b2f(u16 h) {
    union { unsigned u; float f; } x; x.u = ((unsigned)h) << 16; return x.f;
}

// ---------------- stage1: postpre (bids 0-255) + transposes (256-1023) + seed (1024) --
// Proven round-7 version (2-level dependency skip). Postpre is latency-bound:
// transpose/seed blocks run in its shadow and terminate unconditionally.
// NOTE (r8 lesson): do NOT co-schedule extra LLC traffic with the chain — it
// stretches every hop (stage1 53->68us in r8).
__global__ __launch_bounds__(256) void stage1_kernel(const int* __restrict__ ns,
                                                     const int* __restrict__ ch0,
                                                     const int* __restrict__ ch1,
                                                     const int* __restrict__ par,
                                                     const float* __restrict__ W1,
                                                     float* __restrict__ c,
                                                     float* __restrict__ ypost,
                                                     float* __restrict__ y,
                                                     float* __restrict__ flag2,
                                                     const float* __restrict__ W2,
                                                     const float* __restrict__ Wh2,
                                                     const float* __restrict__ Wh1,
                                                     u16* __restrict__ wte,
                                                     u16* __restrict__ wt2,
                                                     u16* __restrict__ WTz1,
                                                     const int* __restrict__ cfl,
                                                     float* __restrict__ outf,
                                                     const float* __restrict__ bh1,
                                                     float* __restrict__ bprime,
                                                     const float* __restrict__ bh3,
                                                     float* __restrict__ outlog) {
    __shared__ float tile[32][33];
    int bid = blockIdx.x, tid = threadIdx.x;

    if (bid < 256) {
        // ======== fused belief prop with 2-LEVEL DEPENDENCY SKIP (proven, verbatim) ==
        int gtid = bid * 256 + tid;
        int wave = gtid >> 6, lane = gtid & 63;
        int j0 = lane * 4;

        // ---- postorder ----
        for (int u = NLEAF + wave; u < NNODES; u += 1024) {
            int a = ch0[u], b = ch1[u];
            int la = ns[a], lb = ns[b];
            const float *ra0, *ra1, *rb0, *rb1;
            int ga0 = -1, ga1 = -1, gb0 = -1, gb1 = -1;
            if (la >= 0) { ra0 = W1 + (long)la * HID; ra1 = ra0; }
            else {
                int x0 = ch0[a], x1 = ch1[a];
                int n0 = ns[x0], n1 = ns[x1];
                if (n0 >= 0) ra0 = W1 + (long)n0 * HID;
                else { ra0 = ypost + (long)x0 * HID; ga0 = x0; }
                if (n1 >= 0) ra1 = W1 + (long)n1 * HID;
                else { ra1 = ypost + (long)x1 * HID; ga1 = x1; }
            }
            if (lb >= 0) { rb0 = W1 + (long)lb * HID; rb1 = rb0; }
            else {
                int x0 = ch0[b], x1 = ch1[b];
                int n0 = ns[x0], n1 = ns[x1];
                if (n0 >= 0) rb0 = W1 + (long)n0 * HID;
                else { rb0 = ypost + (long)x0 * HID; gb0 = x0; }
                if (n1 >= 0) rb1 = W1 + (long)n1 * HID;
                else { rb1 = ypost + (long)x1 * HID; gb1 = x1; }
            }
            float ca0 = 0.f, ca1 = 0.f, cb0 = 0.f, cb1 = 0.f;
            if ((ga0 | ga1 | gb0 | gb1) >= 0) {
                int w0 = ga0 >= 0 ? ga0 : ga1 >= 0 ? ga1 : gb0 >= 0 ? gb0 : gb1;
                float s0, s1, s2, s3;
                spin4(c + (ga0 >= 0 ? ga0 : w0), c + (ga1 >= 0 ? ga1 : w0),
                      c + (gb0 >= 0 ? gb0 : w0), c + (gb1 >= 0 ? gb1 : w0),
                      s0, s1, s2, s3);
                if (ga0 >= 0) ca0 = s0;
                if (ga1 >= 0) ca1 = s1;
                if (gb0 >= 0) cb0 = s2;
                if (gb1 >= 0) cb1 = s3;
            }
            f32x4 qa00, qa01, qa10, qa11, qb00, qb01, qb10, qb11;
            rows4_cv(ra0 + j0, ra1 + j0, rb0 + j0, rb1 + j0,
                     qa00, qa01, qa10, qa11, qb00, qb01, qb10, qb11);
            f32x4 A0, A1, B0, B1; float cA, cB;
            if (la >= 0) { cA = 0.0f; A0 = qa00; A1 = qa01; }
            else {
                cA = 1.0f / (3.0f - (ca0 + ca1));
                A0 = (qa00 + qa10) * cA; A1 = (qa01 + qa11) * cA;
            }
            if (lb >= 0) { cB = 0.0f; B0 = qb00; B1 = qb01; }
            else {
                cB = 1.0f / (3.0f - (cb0 + cb1));
                B0 = (qb00 + qb10) * cB; B1 = (qb01 + qb11) * cB;
            }
            float cu = 1.0f / (3.0f - (cA + cB));
            st_row(ypost + (long)u * HID + j0, (A0 + B0) * cu, (A1 + B1) * cu);
            if (lane == 0) st_flag_ordered(&c[u], cu);
        }

        // ---- preorder ----
        for (int u = ROOT - wave; u >= NLEAF; u -= 1024) {
            float* dst = y + (long)u * HID + j0;
            if (u == ROOT) {
                float cr;
                spin1(c + ROOT, cr);
                f32x4 s0, s1;
                rows1_cv(ypost + (long)ROOT * HID + j0, s0, s1);
                st_row(dst, s0, s1);
            } else {
                int p = par[u];
                if (p == ROOT) {
                    float cr, cu;
                    spin2(c + ROOT, c + u, cr, cu);
                    f32x4 s0, s1, r0, r1;
                    rows2_cv(ypost + (long)u * HID + j0, ypost + (long)ROOT * HID + j0,
                             s0, s1, r0, r1);
                    st_row(dst, fma4(s0, cu, r0), fma4(s1, cu, r1));
                } else {
                    int gp = par[p];
                    float f2, cu, cp;
                    spin3(flag2 + gp, c + u, c + p, f2, cu, cp);
                    f32x4 s0, s1, pp0, pp1, gg0, gg1;
                    rows3_cv(ypost + (long)u * HID + j0, ypost + (long)p * HID + j0,
                             y + (long)gp * HID + j0, s0, s1, pp0, pp1, gg0, gg1);
                    f32x4 yp0 = fma4(pp0, cp, gg0);
                    f32x4 yp1 = fma4(pp1, cp, gg1);
                    st_row(dst, fma4(s0, cu, yp0), fma4(s1, cu, yp1));
                }
            }
            if (lane == 0) st_flag_ordered(&flag2[u], 1.0f);
        }
        return;
    }

    if (bid < 1024) {
        // ======== static transposes: 3 sections of (512x512 fp32) -> bf16 [n][k] =====
        int t = bid - 256;
        int bx = t & 15, by = t >> 4;
        int sec = by >> 4, kt = by & 15;
        int tx = tid & 31, ty = tid >> 5;
        int n0 = bx * 32, k0 = kt * 32;
        const float* src = (sec == 0) ? W2 : (sec == 1) ? Wh2 : (Wh1 + (long)1024 * HID);
        u16* dst = (sec == 0) ? wte : (sec == 1) ? wt2 : WTz1;
        int ld = (sec == 2) ? 1024 : 512;
        int koff = (sec == 2) ? 512 : 0;
#pragma unroll
        for (int i = 0; i < 4; i++)
            tile[ty + i * 8][tx] = src[(long)(k0 + ty + i * 8) * HID + n0 + tx];
        __syncthreads();
#pragma unroll
        for (int i = 0; i < 4; i++)
            dst[(long)(n0 + ty + i * 8) * ld + koff + k0 + tx] = f2bf(tile[tx][ty + i * 8]);
        return;
    }

    // ======== seed block: focal one-hot, logits = b3, bprime = bh1 ===================
    int cf = cfl[0];
    for (int i = tid; i < NLEAF; i += 256) outf[i] = (i == cf) ? 1.0f : 0.0f;
    float b3v = bh3[0];
    for (int i = tid; i < NNODES; i += 256) outlog[i] = b3v;
    for (int i = tid; i < 512; i += 256) bprime[i] = bh1[i];
}

// ---------------- emb fan-out (small): zprep + bvec partials --------------------------
__global__ __launch_bounds__(256) void emb_fan_kernel(const float* __restrict__ emb,
                                                      const float* __restrict__ Wh1,
                                                      u16* __restrict__ WTz1,
                                                      float* __restrict__ bprime) {
    __shared__ float tB[32][33];
    __shared__ float tD[32][33];
    int bid = blockIdx.x, tid = threadIdx.x;
    const float* hf = emb + (long)FOCALR * HID;

    if (bid < 256) {
        // ---- zprep: WTz1[n][k] (k<512) = bf16(W_B + hf[k]*W_D) ----
        int tx = tid & 31, ty = tid >> 5;
        int n0 = (bid & 15) * 32, k0 = (bid >> 4) * 32;
#pragma unroll
        for (int i = 0; i < 4; i++) {
            tB[ty + i * 8][tx] = Wh1[(long)(512 + k0 + ty + i * 8) * HID + n0 + tx];
            tD[ty + i * 8][tx] = Wh1[(long)(1536 + k0 + ty + i * 8) * HID + n0 + tx];
        }
        __syncthreads();
#pragma unroll
        for (int i = 0; i < 4; i++) {
            float hfk = hf[k0 + tx];
            WTz1[(long)(n0 + ty + i * 8) * 1024 + k0 + tx] =
                f2bf(tB[tx][ty + i * 8] + hfk * tD[tx][ty + i * 8]);
        }
        return;
    }
    // ---- bvec partial: atomicAdd into bprime (seeded = bh1 in stage1) ----
    int kc = bid - 256;
    float s0 = 0.0f, s1 = 0.0f;
#pragma unroll 4
    for (int k = kc * 64; k < kc * 64 + 64; k++) {
        float h = hf[k];
        s0 += h * Wh1[(long)k * HID + tid];
        s1 += h * Wh1[(long)k * HID + 256 + tid];
    }
    atomicAdd(bprime + tid, s0);
    atomicAdd(bprime + 256 + tid, s1);
}

// ---------------- GCN neighbor aggregation in 512-d (layer 1) -------------------------
// REDIR: leaf/focal rows read directly from W1 (y rows only exist for internal nodes)
__global__ __launch_bounds__(128) void gcn_agg_kernel(const float* __restrict__ xinf,
                                                      const int* __restrict__ neigh,
                                                      const float* __restrict__ bias,
                                                      const int* __restrict__ ns,
                                                      const int* __restrict__ cfl,
                                                      const float* __restrict__ W1,
                                                      u16* __restrict__ xoutb) {
    int u = blockIdx.x;
    int t = threadIdx.x;
    int n0 = neigh[u * 3 + 0], n1 = neigh[u * 3 + 1], n2 = neigh[u * 3 + 2];
    float deg = 1.0f + (n0 >= 0) + (n1 >= 0) + (n2 >= 0);
    auto rowp = [&](int v) -> const float* {
        if (v == FOCALR) return W1 + (long)cfl[0] * HID;
        int nv = ns[v];
        return (nv >= 0) ? (W1 + (long)nv * HID) : (xinf + (long)v * HID);
    };
    f32x4 s = ldg4(rowp(u) + t * 4);
    if (n0 >= 0) s += ldg4(rowp(n0) + t * 4);
    if (n1 >= 0) s += ldg4(rowp(n1) + t * 4);
    if (n2 >= 0) s += ldg4(rowp(n2) + t * 4);
    s *= (1.0f / deg);
    s += ldg4(bias + t * 4);
    s.x = fmaxf(s.x, 0.f); s.y = fmaxf(s.y, 0.f); s.z = fmaxf(s.z, 0.f); s.w = fmaxf(s.w, 0.f);
    u16x4 h; h[0] = f2bf(s.x); h[1] = f2bf(s.y); h[2] = f2bf(s.z); h[3] = f2bf(s.w);
    *(u16x4*)(xoutb + (long)u * HID + t * 4) = h;
}

// ---------------- bf16 MFMA GEMM v5: 64x128 tile, dbuf pipeline, 1D grid --------------
// bid<512: GEMM tile (bn = (bid&3)*128, bm = (bid>>2)*64 — same order as old 2D grid).
// LOG=1: logits[row] += v * W3[col] via wave-reduce + atomics (outlog seeded with b3).
// AGG=1: A rows generated on the fly = mean of {self, <=3 neighbors} h_bf rows.
// EF=1:  bids >= 512 are ef-row writer blocks (2 rows each), overlapped with the GEMM
//        (pure-BW work vs MFMA/LDS-bound GEMM — complementary resources, no deps).
__device__ __forceinline__ int sw_idx(int row, int kc8) {
    return (row * 8 + (kc8 ^ (row & 7))) * 8;   // u16 index of 16B slot
}

template <int ACT, int AGEN, int LOG, int AGG, int EF>
__global__ __launch_bounds__(256, 3) void gemm_v5(const u16* __restrict__ Abf,
                                                  const u16* __restrict__ WT,
                                                  const float* __restrict__ bias,
                                                  const int* __restrict__ bc,
                                                  const float* __restrict__ tv,
                                                  const float* __restrict__ isr,
                                                  const float* __restrict__ Wtail,
                                                  float* __restrict__ Cf,
                                                  u16* __restrict__ Cbf,
                                                  int M, int K,
                                                  const float* __restrict__ W3,
                                                  float* __restrict__ outlog,
                                                  const int* __restrict__ neigh,
                                                  const float* __restrict__ embf,
                                                  float* __restrict__ efout) {
    __shared__ u16 As[2][64 * 64];
    __shared__ u16 Ws[2][128 * 64];
    if (EF && blockIdx.x >= 512) {
        // ---- ef rows: [hf | ht | |hf-ht| | hf*ht | t_norm | is_root], 2 rows/block ---
        int eb = blockIdx.x - 512;
        int u = eb * 2 + (threadIdx.x >> 7);
        int t = threadIdx.x & 127;
        if (u < NNODES) {
            const float* hfp = embf + (long)FOCALR * HID;
            const float* ht = embf + (long)bc[u] * HID;
            f32x4 f = ldg4(hfp + 4 * t);
            f32x4 h = ldg4(ht + 4 * t);
            float* row = efout + (long)u * EDIM;
            *(f32x4*)(row + 4 * t) = f;
            *(f32x4*)(row + 512 + 4 * t) = h;
            f32x4 d;
            d.x = fabsf(f.x - h.x); d.y = fabsf(f.y - h.y);
            d.z = fabsf(f.z - h.z); d.w = fabsf(f.w - h.w);
            *(f32x4*)(row + 1024 + 4 * t) = d;
            *(f32x4*)(row + 1536 + 4 * t) = f * h;
            if (t == 0) {
                row[2048] = tv[u];
                row[2049] = isr[u];
            }
        }
        return;
    }
    const int tid = threadIdx.x, lane = tid & 63;
    const int wm = (tid >> 6) >> 1, wn = (tid >> 6) & 1;
    const int bid1 = blockIdx.x;
    const int bn = (bid1 & 3) * 128, bm = (bid1 >> 2) * 64;
    const int kq = lane >> 4, lr = lane & 15;
    const int srow = tid >> 3, schunk = tid & 7;
    const int nk = K >> 6;
    floatx4 acc[2][4] = {};

    int btc[2];
    if (AGEN) {
#pragma unroll
        for (int i = 0; i < 2; i++) {
            int gr = bm + srow + i * 32;
            btc[i] = bc[gr < M ? gr : 0];
        }
    }
    int nbr[2][3];
    float invdeg[2];
    if (AGG) {
#pragma unroll
        for (int i = 0; i < 2; i++) {
            int gr = bm + srow + i * 32;
            int v0 = neigh[gr * 3 + 0], v1 = neigh[gr * 3 + 1], v2 = neigh[gr * 3 + 2];
            nbr[i][0] = v0; nbr[i][1] = v1; nbr[i][2] = v2;
            invdeg[i] = 1.0f / (1.0f + (v0 >= 0) + (v1 >= 0) + (v2 >= 0));
        }
    }

    u16x8 pf_hf, pf_a[2], pf_b[4], pf_n[2][3];

    auto prefetch = [&](int kk) {
        if (AGEN) {
            int cb = (kk & 7) * 64 + schunk * 8;
            pf_hf = *(const u16x8*)(Abf + (long)FOCALR * HID + cb);
#pragma unroll
            for (int i = 0; i < 2; i++)
                pf_a[i] = *(const u16x8*)(Abf + (long)btc[i] * HID + cb);
        } else if (AGG) {
            long kof = (long)(kk * 64 + schunk * 8);
#pragma unroll
            for (int i = 0; i < 2; i++) {
                int gr = bm + srow + i * 32;
                pf_a[i] = *(const u16x8*)(Abf + (long)gr * HID + kof);
#pragma unroll
                for (int k = 0; k < 3; k++)
                    pf_n[i][k] = (nbr[i][k] >= 0)
                        ? *(const u16x8*)(Abf + (long)nbr[i][k] * HID + kof)
                        : (u16x8){0, 0, 0, 0, 0, 0, 0, 0};
            }
        } else {
            long kof = (long)(kk * 64 + schunk * 8);
#pragma unroll
            for (int i = 0; i < 2; i++) {
                int gr = bm + srow + i * 32;
                if (gr < M) pf_a[i] = *(const u16x8*)(Abf + (long)gr * K + kof);
                else        pf_a[i] = (u16x8){0,0,0,0,0,0,0,0};
            }
        }
#pragma unroll
        for (int i = 0; i < 4; i++)
            pf_b[i] = *(const u16x8*)(WT + (long)(bn + srow + i * 32) * K + kk * 64 + schunk * 8);
    };

    auto commit = [&](int kk, int buf) {
        if (AGEN) {
            int sec = kk >> 3;
#pragma unroll
            for (int i = 0; i < 2; i++) {
                u16x8 v;
                if (sec == 0) v = pf_a[i];
                else {
#pragma unroll
                    for (int q = 0; q < 8; q++) v[q] = f2bf(fabsf(b2f(pf_hf[q]) - b2f(pf_a[i][q])));
                }
                if (bm + srow + i * 32 >= M) v = (u16x8){0,0,0,0,0,0,0,0};
                *(u16x8*)&As[buf][sw_idx(srow + i * 32, schunk)] = v;
            }
        } else if (AGG) {
#pragma unroll
            for (int i = 0; i < 2; i++) {
                u16x8 v;
#pragma unroll
                for (int q = 0; q < 8; q++) {
                    float s = b2f(pf_a[i][q]);
                    s += b2f(pf_n[i][0][q]);
                    s += b2f(pf_n[i][1][q]);
                    s += b2f(pf_n[i][2][q]);
                    v[q] = f2bf(s * invdeg[i]);
                }
                *(u16x8*)&As[buf][sw_idx(srow + i * 32, schunk)] = v;
            }
        } else {
#pragma unroll
            for (int i = 0; i < 2; i++)
                *(u16x8*)&As[buf][sw_idx(srow + i * 32, schunk)] = pf_a[i];
        }
#pragma unroll
        for (int i = 0; i < 4; i++)
            *(u16x8*)&Ws[buf][sw_idx(srow + i * 32, schunk)] = pf_b[i];
    };

    prefetch(0);
    commit(0, 0);
    __syncthreads();

    for (int kk = 0; kk < nk; kk++) {
        int cur = kk & 1;
        bool more = (kk + 1) < nk;
        if (more) prefetch(kk + 1);
#pragma unroll
        for (int kc = 0; kc < 2; kc++) {
            short8 af[2], bf8[4];
#pragma unroll
            for (int t2 = 0; t2 < 2; t2++)
                af[t2]  = *(short8*)&As[cur][sw_idx(wm * 32 + t2 * 16 + lr, kc * 4 + kq)];
#pragma unroll
            for (int t2 = 0; t2 < 4; t2++)
                bf8[t2] = *(short8*)&Ws[cur][sw_idx(wn * 64 + t2 * 16 + lr, kc * 4 + kq)];
#pragma unroll
            for (int i2 = 0; i2 < 2; i2++)
#pragma unroll
                for (int j = 0; j < 4; j++)
                    acc[i2][j] = __builtin_amdgcn_mfma_f32_16x16x32_bf16(af[i2], bf8[j], acc[i2][j], 0, 0, 0);
        }
        if (more) {
            __syncthreads();
            commit(kk + 1, cur ^ 1);
            __syncthreads();
        }
    }

    // ---- epilogue: row=(lane>>4)*4+reg, col=lane&15 ----
    float lsum[2][4] = {};
    float w3v[4] = {};
    if (LOG) {
#pragma unroll
        for (int j = 0; j < 4; j++) w3v[j] = W3[bn + wn * 64 + j * 16 + lr];
    }
#pragma unroll
    for (int i = 0; i < 2; i++) {
        int row0 = bm + wm * 32 + i * 16 + kq * 4;
#pragma unroll
        for (int j = 0; j < 4; j++) {
            int col = bn + wn * 64 + j * 16 + lr;
            float bv = bias[col];
            float t0 = 0.f, t1 = 0.f;
            if (AGEN) { t0 = Wtail[col]; t1 = Wtail[512 + col]; }
#pragma unroll
            for (int r = 0; r < 4; r++) {
                int gr = row0 + r;
                if (gr < M) {
                    float v = acc[i][j][r] + bv;
                    if (AGEN) v += tv[gr] * t0 + isr[gr] * t1;
                    if (ACT == 2) v = (v > 0.0f) ? v : (expf(v) - 1.0f);
                    if (LOG) lsum[i][r] += v * w3v[j];
                    if (Cf)  Cf[(long)gr * HID + col] = v;
                    if (Cbf) Cbf[(long)gr * HID + col] = f2bf(v);
                }
            }
        }
    }
    if (LOG) {
#pragma unroll
        for (int i = 0; i < 2; i++) {
            int row0 = bm + wm * 32 + i * 16 + kq * 4;
#pragma unroll
            for (int r = 0; r < 4; r++) {
                float s = lsum[i][r];
                s += __shfl_xor(s, 1);
                s += __shfl_xor(s, 2);
                s += __shfl_xor(s, 4);
                s += __shfl_xor(s, 8);
                if (lr == 0) {
                    int gr = row0 + r;
                    if (gr < M) atomicAdd(outlog + gr, s);
                }
            }
        }
    }
}

// ---------------- softmax over 8191 logits (single block) -----------------------------
__global__ __launch_bounds__(1024) void softmax_kernel(const float* __restrict__ lg,
                                                       float* __restrict__ probs) {
    __shared__ float red[16];
    __shared__ float gmax_s, gsum_s;
    int t = threadIdx.x, wid = t >> 6, lane = t & 63;
    float m = -3.4e38f;
    for (int i = t; i < NNODES; i += 1024) m = fmaxf(m, lg[i]);
    for (int o = 32; o; o >>= 1) m = fmaxf(m, __shfl_down(m, o));
    if (lane == 0) red[wid] = m;
    __syncthreads();
    if (t == 0) {
        float g = red[0];
        for (int i = 1; i < 16; i++) g = fmaxf(g, red[i]);
        gmax_s = g;
    }
    __syncthreads();
    float gmax = gmax_s;
    float s = 0.0f;
    for (int i = t; i < NNODES; i += 1024) s += expf(lg[i] - gmax);
    for (int o = 32; o; o >>= 1) s += __shfl_down(s, o);
    if (lane == 0) red[wid] = s;
    __syncthreads();
    if (t == 0) {
        float g = 0.0f;
        for (int i = 0; i < 16; i++) g += red[i];
        gsum_s = g;
    }
    __syncthreads();
    float inv = 1.0f / gsum_s;
    for (int i = t; i < NNODES; i += 1024) probs[i] = expf(lg[i] - gmax) * inv;
}

extern "C" void kernel_launch(void* const* d_in, const int* in_sizes, int n_in,
                              void* d_out, int out_size, void* d_ws, size_t ws_size,
                              hipStream_t stream) {
    const int*   ns    = (const int*)d_in[0];
    const int*   ch0   = (const int*)d_in[1];
    const int*   ch1   = (const int*)d_in[2];
    const int*   par   = (const int*)d_in[3];
    const int*   neigh = (const int*)d_in[4];
    const int*   bc    = (const int*)d_in[5];
    const int*   cfl   = (const int*)d_in[6];
    const float* tv    = (const float*)d_in[7];
    const float* isr   = (const float*)d_in[8];
    const float* W1    = (const float*)d_in[9];
    const float* b1    = (const float*)d_in[10];
    const float* W2    = (const float*)d_in[11];
    const float* b2    = (const float*)d_in[12];
    const float* Wh1   = (const float*)d_in[13];
    const float* bh1   = (const float*)d_in[14];
    const float* Wh2   = (const float*)d_in[15];
    const float* bh2   = (const float*)d_in[16];
    const float* Wh3   = (const float*)d_in[17];
    const float* bh3   = (const float*)d_in[18];

    float* out = (float*)d_out;
    float* out_logits = out + OUT_LOGITS;
    float* out_probs  = out + OUT_PROBS;
    float* out_ef     = out + OUT_EF;
    float* out_emb    = out + OUT_EMB;
    float* out_focal  = out + OUT_FOCAL;

    const size_t MB = 1024 * 1024;
    char* ws = (char*)d_ws;
    float* c      = (float*)(ws);                    // 8191 floats
    float* flag2  = (float*)(ws + 40960);            // 8192 floats
    float* buf0   = (float*)(ws + 81920);            // 16 MB: ypost
    float* buf1   = (float*)(ws + 81920 + 16 * MB);  // 16 MB: y -> emb_bf (high half)
    float* buf2   = (float*)(ws + 81920 + 32 * MB);  // 16 MB: h_bf -> z1_bf
    u16*   wte    = (u16*)  (ws + 81920 + 48 * MB);          // 512x512  bf16 = 0.5 MB
    u16*   wt2    = (u16*)  (ws + 81920 + 48 * MB + 512 * 1024);
    u16*   wtz1   = (u16*)  (ws + 81920 + 49 * MB);          // 512x1024 bf16 = 1 MB
    float* bprime = (float*)(ws + 81920 + 50 * MB);          // 512 floats

    float* ypost  = buf0;
    float* y      = buf1;
    u16*   emb_bf = (u16*)((char*)buf1 + 8 * MB);
    u16*   h_bf   = (u16*)buf2;
    u16*   z1_bf  = (u16*)buf2;

    // stage1: tree recursions + (in their latency shadow) weight transposes, focal
    // one-hot, logits/bprime seeding
    stage1_kernel<<<dim3(1025), dim3(256), 0, stream>>>(ns, ch0, ch1, par, W1, c, ypost,
                                                        y, flag2, W2, Wh2, Wh1, wte, wt2,
                                                        wtz1, cfl, out_focal, bh1, bprime,
                                                        bh3, out_logits);
    // GCN layer 1: h_bf = bf16(relu(agg(y) + b1)), leaf/focal rows redirected to W1
    gcn_agg_kernel<<<dim3(NROWS), dim3(128), 0, stream>>>(y, neigh, b1, ns, cfl, W1, h_bf);
    // emb = agg(h_bf) @ W2 + b2 (GCN layer-2 aggregation fused into A-staging)
    gemm_v5<0, 0, 0, 1, 0><<<dim3(512), dim3(256), 0, stream>>>(
        h_bf, wte, b2, nullptr, nullptr, nullptr, nullptr, out_emb, emb_bf,
        NROWS, HID, nullptr, nullptr, neigh, nullptr, nullptr);
    // small fan-out: z1 weight fold + bias fold partials
    emb_fan_kernel<<<dim3(264), dim3(256), 0, stream>>>(out_emb, Wh1, wtz1, bprime);
    // z1 = elu([ht | |hf-ht|] @ WTz1 + ...), with ef-row writer blocks overlapped
    gemm_v5<2, 1, 0, 0, 1><<<dim3(4608), dim3(256), 0, stream>>>(
        emb_bf, wtz1, bprime, bc, tv, isr, Wh1 + (long)2048 * HID, nullptr, z1_bf,
        NNODES, 1024, nullptr, nullptr, nullptr, out_emb, out_ef);
    // z2 = elu(z1 @ Wh2 + bh2); logits folded into epilogue (no z2 store at all)
    gemm_v5<2, 0, 1, 0, 0><<<dim3(512), dim3(256), 0, stream>>>(
        z1_bf, wt2, bh2, nullptr, nullptr, nullptr, nullptr, nullptr, nullptr,
        NNODES, HID, Wh3, out_logits, nullptr, nullptr, nullptr);
    softmax_kernel<<<dim3(1), dim3(1024), 0, stream>>>(out_logits, out_probs);
}